// Round 1
// baseline (293.855 us; speedup 1.0000x reference)
//
#include <hip/hip_runtime.h>
#include <hip/hip_bf16.h>

#define T_TOT 2304
#define DDIM  1024
#define NH    16
#define DK    64
#define SLEN  128
#define SEQ   2048

typedef __bf16 bf16x8 __attribute__((ext_vector_type(8)));
typedef float  f32x4  __attribute__((ext_vector_type(4)));

__device__ __forceinline__ void async_copy16(const void* gsrc, void* ldst) {
  __builtin_amdgcn_global_load_lds(
      (const __attribute__((address_space(1))) void*)gsrc,
      (__attribute__((address_space(3))) void*)ldst, 16, 0, 0);
}

// ---------------- conversion: x -> bf16 ; W[h][d][n] -> Wt (bf16) [m][h][n][d]
__global__ void convert_kernel(const float* __restrict__ x,
                               const float* __restrict__ Wq, const float* __restrict__ Wk,
                               const float* __restrict__ Wv, const float* __restrict__ Wqs,
                               const float* __restrict__ Wks, const float* __restrict__ Wvs,
                               __bf16* __restrict__ xb, __bf16* __restrict__ Wt) {
  const int XN = T_TOT * DDIM;          // 2359296
  const int WN = NH * DDIM * DK;        // 1048576 = 2^20
  const int TOT = XN + 6 * WN;
  int stride = gridDim.x * blockDim.x;
  for (int i = blockIdx.x * blockDim.x + threadIdx.x; i < TOT; i += stride) {
    if (i < XN) {
      xb[i] = (__bf16)x[i];
    } else {
      int r  = i - XN;
      int m  = r >> 20;
      int rr = r & (WN - 1);
      int h   = rr >> 16;         // D*DK = 65536
      int rem = rr & 65535;
      int d   = rem >> 6;
      int jj  = rem & 63;
      const float* W = m == 0 ? Wq : m == 1 ? Wk : m == 2 ? Wv
                      : m == 3 ? Wqs : m == 4 ? Wks : Wvs;
      Wt[((size_t)m << 20) + (h << 16) + jj * DDIM + d] = (__bf16)W[rr];
    }
  }
}

// ---------------- projection + l2norm: out[which][h][t][n] (bf16, row-normalized)
__global__ __launch_bounds__(256) void proj_kernel(
    const __bf16* __restrict__ xb, const __bf16* __restrict__ Wt,
    __bf16* __restrict__ qkv) {
  const int which = blockIdx.x;   // 0=q 1=k 2=v
  const int rt    = blockIdx.y;   // 0..17  (128-row tiles)
  const int h     = blockIdx.z;
  const int r0    = rt * 128;
  const int m     = (rt == 0 || rt == 17) ? which + 3 : which;  // state vs main weights

  __shared__ __bf16 Xs[128 * 32];   // 8 KB, XOR-swizzled 16B chunks
  __shared__ __bf16 Wsh[64 * 32];   // 4 KB

  const int tid  = threadIdx.x;
  const int wave = tid >> 6, lane = tid & 63;
  const int quad = lane >> 4, lc = lane & 15;

  const __bf16* Wbase = Wt + ((size_t)m * NH + h) * (DK * DDIM);

  const f32x4 fz = {0.f, 0.f, 0.f, 0.f};
  f32x4 acc[2][4];
#pragma unroll
  for (int i = 0; i < 2; i++)
#pragma unroll
    for (int j = 0; j < 4; j++) acc[i][j] = fz;

  for (int k0 = 0; k0 < DDIM; k0 += 32) {
    // stage X tile 128x32 (512 x 16B chunks), swizzle c' = c ^ ((row>>1)&3)
#pragma unroll
    for (int it = 0; it < 2; ++it) {
      int L = it * 256 + wave * 64 + lane;
      int row = L >> 2, cpos = L & 3;
      int c = cpos ^ ((row >> 1) & 3);
      async_copy16(xb + (size_t)(r0 + row) * DDIM + k0 + c * 8,
                   (char*)Xs + (size_t)(it * 256 + wave * 64) * 16);
    }
    {
      int L = wave * 64 + lane;
      int row = L >> 2, cpos = L & 3;
      int c = cpos ^ ((row >> 1) & 3);
      async_copy16(Wbase + (size_t)row * DDIM + k0 + c * 8,
                   (char*)Wsh + (size_t)(wave * 64) * 16);
    }
    __syncthreads();
    bf16x8 afr[2], bfr[4];
#pragma unroll
    for (int i = 0; i < 2; i++) {
      int row = wave * 32 + i * 16 + lc;
      int slot = row * 4 + (quad ^ ((row >> 1) & 3));
      afr[i] = *(const bf16x8*)(Xs + slot * 8);
    }
#pragma unroll
    for (int j = 0; j < 4; j++) {
      int row = j * 16 + lc;
      int slot = row * 4 + (quad ^ ((row >> 1) & 3));
      bfr[j] = *(const bf16x8*)(Wsh + slot * 8);
    }
#pragma unroll
    for (int i = 0; i < 2; i++)
#pragma unroll
      for (int j = 0; j < 4; j++)
        acc[i][j] = __builtin_amdgcn_mfma_f32_16x16x32_bf16(afr[i], bfr[j], acc[i][j], 0, 0, 0);
    __syncthreads();
  }

  // epilogue: fp32 row l2norm, store bf16
  __bf16* outp = qkv + ((size_t)which * NH + h) * ((size_t)T_TOT * DK);
#pragma unroll
  for (int i = 0; i < 2; i++) {
#pragma unroll
    for (int r = 0; r < 4; r++) {
      float s = 0.f;
#pragma unroll
      for (int j = 0; j < 4; j++) { float v = acc[i][j][r]; s += v * v; }
#pragma unroll
      for (int off = 1; off < 16; off <<= 1) s += __shfl_xor(s, off, 64);
      float inv = 1.0f / fmaxf(sqrtf(s), 1e-12f);
      int row = r0 + wave * 32 + i * 16 + quad * 4 + r;
#pragma unroll
      for (int j = 0; j < 4; j++)
        outp[(size_t)row * DK + j * 16 + lc] = (__bf16)(acc[i][j][r] * inv);
    }
  }
}

// ---------------- flash attention, BM=BN=64, causal + state mask
__global__ __launch_bounds__(256) void attn_kernel(
    const __bf16* __restrict__ qkv, const float* __restrict__ scaling,
    float* __restrict__ out) {
  const int h  = blockIdx.y;
  const int qt = (int)(gridDim.x - 1u - blockIdx.x);  // reverse: big-work blocks first
  const int q0 = qt * 64;
  const __bf16* qp = qkv + ((size_t)(0 * NH + h)) * ((size_t)T_TOT * DK);
  const __bf16* kp = qkv + ((size_t)(1 * NH + h)) * ((size_t)T_TOT * DK);
  const __bf16* vp = qkv + ((size_t)(2 * NH + h)) * ((size_t)T_TOT * DK);
  const float scale = scaling[h];

  __shared__ __bf16 Ks[64 * 64];      // [kv][d], swizzled chunks
  __shared__ __bf16 Vt[64 * 64];      // [d][kv], swizzled chunks
  __shared__ __bf16 Ps[4][16 * 64];   // per-wave P tile [qrow][kv], swizzled

  const int tid  = threadIdx.x;
  const int wave = tid >> 6, lane = tid & 63;
  const int quad = lane >> 4, lc = lane & 15;

  bf16x8 qf[2];
  {
    int qrow = q0 + wave * 16 + lc;
    qf[0] = *(const bf16x8*)(qp + (size_t)qrow * DK + quad * 8);
    qf[1] = *(const bf16x8*)(qp + (size_t)qrow * DK + 32 + quad * 8);
  }

  const f32x4 fz = {0.f, 0.f, 0.f, 0.f};
  f32x4 acc_o[4];
#pragma unroll
  for (int ct = 0; ct < 4; ct++) acc_o[ct] = fz;
  float m_i[4], l_i[4];
#pragma unroll
  for (int r = 0; r < 4; r++) { m_i[r] = -__builtin_inff(); l_i[r] = 0.f; }

  const int jstart = (q0 >= SLEN + SEQ) ? 2 : 0;  // state rows can't see cols < 128
  for (int j = jstart; j <= qt; ++j) {
    const int c0 = j * 64;
    // stage K natural layout via direct-to-LDS, swizzle c' = c ^ (row&7)
#pragma unroll
    for (int it = 0; it < 2; ++it) {
      int L = it * 256 + wave * 64 + lane;
      int row = L >> 3, cpos = L & 7;
      int c = cpos ^ (row & 7);
      async_copy16(kp + (size_t)(c0 + row) * DK + c * 8,
                   (char*)Ks + (size_t)(it * 256 + wave * 64) * 16);
    }
    // stage V transposed (manual scatter)
#pragma unroll
    for (int it = 0; it < 2; ++it) {
      int chunk = it * 256 + tid;
      int row = chunk >> 3, kg = chunk & 7;
      bf16x8 vv = *(const bf16x8*)(vp + (size_t)(c0 + row) * DK + kg * 8);
#pragma unroll
      for (int e = 0; e < 8; e++) {
        int d = kg * 8 + e;
        int slotc = (row >> 3) ^ (d & 7);
        Vt[d * 64 + slotc * 8 + (row & 7)] = vv[e];
      }
    }
    __syncthreads();

    // S = Q K^T  (16 q-rows x 64 kv)
    f32x4 s[4];
#pragma unroll
    for (int ct = 0; ct < 4; ct++) {
      s[ct] = fz;
#pragma unroll
      for (int kk = 0; kk < 2; kk++) {
        int row = ct * 16 + lc;
        int slot = row * 8 + ((kk * 4 + quad) ^ (row & 7));
        bf16x8 bf = *(const bf16x8*)(Ks + slot * 8);
        s[ct] = __builtin_amdgcn_mfma_f32_16x16x32_bf16(qf[kk], bf, s[ct], 0, 0, 0);
      }
    }

    // online softmax (fp32, quad-shuffles; C layout: row=quad*4+r, col=ct*16+lc)
    float p[4][4];
#pragma unroll
    for (int r = 0; r < 4; r++) {
      const int R = q0 + wave * 16 + quad * 4 + r;
      float mx = -__builtin_inff();
#pragma unroll
      for (int ct = 0; ct < 4; ct++) {
        float val = s[ct][r] * scale;
        if (j == qt && (c0 + ct * 16 + lc) > R) val = -__builtin_inff();
        p[r][ct] = val;
        mx = fmaxf(mx, val);
      }
#pragma unroll
      for (int off = 1; off < 16; off <<= 1) mx = fmaxf(mx, __shfl_xor(mx, off, 64));
      float mnew  = fmaxf(m_i[r], mx);
      float alpha = __expf(m_i[r] - mnew);
      float rs = 0.f;
#pragma unroll
      for (int ct = 0; ct < 4; ct++) {
        float pe = __expf(p[r][ct] - mnew);
        p[r][ct] = pe;
        rs += pe;
      }
#pragma unroll
      for (int off = 1; off < 16; off <<= 1) rs += __shfl_xor(rs, off, 64);
      l_i[r] = l_i[r] * alpha + rs;
      m_i[r] = mnew;
#pragma unroll
      for (int ct = 0; ct < 4; ct++) acc_o[ct][r] *= alpha;
      // write P (bf16) to per-wave LDS region, swizzled
#pragma unroll
      for (int ct = 0; ct < 4; ct++) {
        int col = ct * 16 + lc;
        int mrow = quad * 4 + r;
        int slotc = (col >> 3) ^ (mrow & 7);
        Ps[wave][mrow * 64 + slotc * 8 + (col & 7)] = (__bf16)p[r][ct];
      }
    }

    // O += P V   (A = P from wave-local LDS, B = V^T from LDS)
#pragma unroll
    for (int kk = 0; kk < 2; kk++) {
      int slot = lc * 8 + ((kk * 4 + quad) ^ (lc & 7));
      bf16x8 pa = *(const bf16x8*)(&Ps[wave][0] + slot * 8);
#pragma unroll
      for (int ct = 0; ct < 4; ct++) {
        int vrow = ct * 16 + lc;
        int vslot = vrow * 8 + ((kk * 4 + quad) ^ (vrow & 7));
        bf16x8 vb = *(const bf16x8*)(Vt + vslot * 8);
        acc_o[ct] = __builtin_amdgcn_mfma_f32_16x16x32_bf16(pa, vb, acc_o[ct], 0, 0, 0);
      }
    }
    __syncthreads();
  }

  // epilogue: O / l, fp32 store (layout bhqd)
#pragma unroll
  for (int r = 0; r < 4; r++) {
    const int R = q0 + wave * 16 + quad * 4 + r;
    float invl = 1.0f / l_i[r];
#pragma unroll
    for (int ct = 0; ct < 4; ct++)
      out[((size_t)h * T_TOT + R) * DK + ct * 16 + lc] = acc_o[ct][r] * invl;
  }
}

extern "C" void kernel_launch(void* const* d_in, const int* in_sizes, int n_in,
                              void* d_out, int out_size, void* d_ws, size_t ws_size,
                              hipStream_t stream) {
  const float* x    = (const float*)d_in[0];
  const float* Wq   = (const float*)d_in[1];
  const float* Wk   = (const float*)d_in[2];
  const float* Wv   = (const float*)d_in[3];
  const float* Wqs  = (const float*)d_in[4];
  const float* Wks  = (const float*)d_in[5];
  const float* Wvs  = (const float*)d_in[6];
  const float* scal = (const float*)d_in[7];
  float* out = (float*)d_out;

  char* ws = (char*)d_ws;
  __bf16* xb  = (__bf16*)ws;                                            // 4.72 MB
  __bf16* Wt  = (__bf16*)(ws + (size_t)T_TOT * DDIM * 2);               // 12.6 MB
  __bf16* qkv = (__bf16*)(ws + (size_t)T_TOT * DDIM * 2
                             + (size_t)6 * NH * DK * DDIM * 2);         // 14.2 MB

  convert_kernel<<<2048, 256, 0, stream>>>(x, Wq, Wk, Wv, Wqs, Wks, Wvs, xb, Wt);
  proj_kernel<<<dim3(3, 18, NH), 256, 0, stream>>>(xb, Wt, qkv);
  attn_kernel<<<dim3(36, NH), 256, 0, stream>>>(qkv, scal, out);
}

// Round 2
// 243.642 us; speedup vs baseline: 1.2061x; 1.2061x over previous
//
#include <hip/hip_runtime.h>
#include <hip/hip_bf16.h>

#define T_TOT 2304
#define DDIM  1024
#define NH    16
#define DK    64
#define SLEN  128
#define SEQ   2048

typedef __bf16 bf16x8 __attribute__((ext_vector_type(8)));
typedef __bf16 bf16x4 __attribute__((ext_vector_type(4)));
typedef float  f32x4  __attribute__((ext_vector_type(4)));

__device__ __forceinline__ void async_copy16(const void* gsrc, void* ldst) {
  __builtin_amdgcn_global_load_lds(
      (const __attribute__((address_space(1))) void*)gsrc,
      (__attribute__((address_space(3))) void*)ldst, 16, 0, 0);
}

// ---------------- convert: x -> bf16 (vectorized); W[h][d][n] -> Wt[m][h][n][d] via LDS transpose
__global__ __launch_bounds__(256) void convert_kernel(
    const float* __restrict__ x,
    const float* __restrict__ Wq, const float* __restrict__ Wk,
    const float* __restrict__ Wv, const float* __restrict__ Wqs,
    const float* __restrict__ Wks, const float* __restrict__ Wvs,
    __bf16* __restrict__ xb, __bf16* __restrict__ Wt) {
  const int b = blockIdx.x;
  const int tid = threadIdx.x;
  if (b < 576) {
    // x: 2359296 floats = 576 blocks * 1024 float4
    const float4* xin = (const float4*)x;
#pragma unroll
    for (int it = 0; it < 4; ++it) {
      int idx4 = b * 1024 + it * 256 + tid;
      float4 v = xin[idx4];
      bf16x4 o;
      o[0] = (__bf16)v.x; o[1] = (__bf16)v.y; o[2] = (__bf16)v.z; o[3] = (__bf16)v.w;
      *(bf16x4*)(xb + (size_t)idx4 * 4) = o;
    }
    return;
  }
  // W transpose: 1536 blocks: m(6) x h(16) x dtile(16); 64(d) x 64(n) tile
  __shared__ float tile[64 * 65];
  const int wb = b - 576;
  const int m  = wb >> 8;
  const int rem = wb & 255;
  const int h  = rem >> 4;
  const int dt = rem & 15;
  const int d0 = dt * 64;
  const float* Wsrc = (m == 0 ? Wq : m == 1 ? Wk : m == 2 ? Wv
                      : m == 3 ? Wqs : m == 4 ? Wks : Wvs) + (size_t)h * (DDIM * DK);
#pragma unroll
  for (int rr = 0; rr < 4; ++rr) {
    int drow = rr * 16 + (tid >> 4);
    int nc   = (tid & 15) * 4;
    float4 v = *(const float4*)(Wsrc + (size_t)(d0 + drow) * DK + nc);
    tile[(nc + 0) * 65 + drow] = v.x;
    tile[(nc + 1) * 65 + drow] = v.y;
    tile[(nc + 2) * 65 + drow] = v.z;
    tile[(nc + 3) * 65 + drow] = v.w;
  }
  __syncthreads();
  {
    int n  = tid >> 2;
    int rg = (tid & 3) * 16;
    __bf16* dst = Wt + (((size_t)(m * NH + h)) * DK + n) * DDIM + d0 + rg;
    bf16x8 o0, o1;
#pragma unroll
    for (int e = 0; e < 8; e++) o0[e] = (__bf16)tile[n * 65 + rg + e];
#pragma unroll
    for (int e = 0; e < 8; e++) o1[e] = (__bf16)tile[n * 65 + rg + 8 + e];
    *(bf16x8*)dst = o0;
    *(bf16x8*)(dst + 8) = o1;
  }
}

// ---------------- projection + l2norm (+q prescale, v transposed store)
__global__ __launch_bounds__(256) void proj_kernel(
    const __bf16* __restrict__ xb, const __bf16* __restrict__ Wt,
    const float* __restrict__ scal,
    __bf16* __restrict__ qkv, __bf16* __restrict__ vt) {
  const int which = blockIdx.x;   // 0=q 1=k 2=v
  const int rt    = blockIdx.y;   // 0..17
  const int h     = blockIdx.z;
  const int r0    = rt * 128;
  const int m     = (rt == 0 || rt == 17) ? which + 3 : which;

  __shared__ __bf16 Xs[128 * 64];   // 16 KB
  __shared__ __bf16 Wsh[64 * 64];   // 8 KB

  const int tid  = threadIdx.x;
  const int wave = tid >> 6, lane = tid & 63;
  const int quad = lane >> 4, lc = lane & 15;

  const __bf16* Wbase = Wt + ((size_t)(m * NH + h)) * (DK * DDIM);

  const f32x4 fz = {0.f, 0.f, 0.f, 0.f};
  f32x4 acc[2][4];
#pragma unroll
  for (int i = 0; i < 2; i++)
#pragma unroll
    for (int j = 0; j < 4; j++) acc[i][j] = fz;

  for (int k0 = 0; k0 < DDIM; k0 += 64) {
    // X tile 128x64: 1024 16B chunks, 8 chunks/row, swizzle c' = c ^ (row&7)
#pragma unroll
    for (int it = 0; it < 4; ++it) {
      int L = it * 256 + tid;
      int row = L >> 3, c = (L & 7) ^ ((L >> 3) & 7);
      async_copy16(xb + (size_t)(r0 + row) * DDIM + k0 + c * 8,
                   (char*)Xs + (size_t)(it * 256 + wave * 64) * 16);
    }
#pragma unroll
    for (int it = 0; it < 2; ++it) {
      int L = it * 256 + tid;
      int row = L >> 3, c = (L & 7) ^ ((L >> 3) & 7);
      async_copy16(Wbase + (size_t)row * DDIM + k0 + c * 8,
                   (char*)Wsh + (size_t)(it * 256 + wave * 64) * 16);
    }
    __syncthreads();
    bf16x8 afr[2][2], bfr[2][4];
#pragma unroll
    for (int kk = 0; kk < 2; kk++) {
#pragma unroll
      for (int i = 0; i < 2; i++) {
        int row = wave * 32 + i * 16 + lc;
        int ch  = (kk * 4 + quad) ^ (row & 7);
        afr[kk][i] = *(const bf16x8*)(Xs + (row * 8 + ch) * 8);
      }
#pragma unroll
      for (int j = 0; j < 4; j++) {
        int row = j * 16 + lc;
        int ch  = (kk * 4 + quad) ^ (row & 7);
        bfr[kk][j] = *(const bf16x8*)(Wsh + (row * 8 + ch) * 8);
      }
    }
#pragma unroll
    for (int kk = 0; kk < 2; kk++)
#pragma unroll
      for (int i = 0; i < 2; i++)
#pragma unroll
        for (int j = 0; j < 4; j++)
          acc[i][j] = __builtin_amdgcn_mfma_f32_16x16x32_bf16(afr[kk][i], bfr[kk][j], acc[i][j], 0, 0, 0);
    __syncthreads();
  }

  // epilogue: fp32 row l2norm (+ scale for q)
  float inv4[2][4];
  const float qscale = (which == 0) ? scal[h] : 1.0f;
#pragma unroll
  for (int i = 0; i < 2; i++) {
#pragma unroll
    for (int r = 0; r < 4; r++) {
      float s = 0.f;
#pragma unroll
      for (int j = 0; j < 4; j++) { float v = acc[i][j][r]; s += v * v; }
#pragma unroll
      for (int off = 1; off < 16; off <<= 1) s += __shfl_xor(s, off, 64);
      inv4[i][r] = qscale / fmaxf(sqrtf(s), 1e-12f);
    }
  }
  if (which == 2) {
    __bf16* vtp = vt + (size_t)h * (DK * T_TOT);
#pragma unroll
    for (int i = 0; i < 2; i++) {
      int rowbase = r0 + wave * 32 + i * 16 + quad * 4;
#pragma unroll
      for (int j = 0; j < 4; j++) {
        bf16x4 o;
#pragma unroll
        for (int r = 0; r < 4; r++) o[r] = (__bf16)(acc[i][j][r] * inv4[i][r]);
        *(bf16x4*)(vtp + (size_t)(j * 16 + lc) * T_TOT + rowbase) = o;
      }
    }
  } else {
    __bf16* outp = qkv + ((size_t)(which * NH + h)) * ((size_t)T_TOT * DK);
#pragma unroll
    for (int i = 0; i < 2; i++)
#pragma unroll
      for (int r = 0; r < 4; r++) {
        int row = r0 + wave * 32 + i * 16 + quad * 4 + r;
#pragma unroll
        for (int j = 0; j < 4; j++)
          outp[(size_t)row * DK + j * 16 + lc] = (__bf16)(acc[i][j][r] * inv4[i][r]);
      }
  }
}

// ---------------- flash attention: barrier-free, one wave per 16-row q tile
__global__ __launch_bounds__(256) void attn_kernel(
    const __bf16* __restrict__ qkv, const __bf16* __restrict__ vt,
    float* __restrict__ out) {
  const int b    = blockIdx.x;          // 0..575
  const int h    = b & 15;              // same head -> same XCD (b%8 pattern)
  const int qg   = 35 - (b >> 4);       // 64-row group, big work first
  const int tid  = threadIdx.x;
  const int wave = tid >> 6, lane = tid & 63;
  const int quad = lane >> 4, lc = lane & 15;
  const int qt16 = qg * 4 + wave;       // 16-row tile 0..143
  const int q0w  = qt16 * 16;

  const __bf16* qp = qkv + ((size_t)h) * ((size_t)T_TOT * DK);
  const __bf16* kp = qkv + ((size_t)(NH + h)) * ((size_t)T_TOT * DK);
  const __bf16* vp = vt + (size_t)h * (DK * T_TOT);

  __shared__ __bf16 Ps[4][16 * 64];

  bf16x8 qf[2];
#pragma unroll
  for (int kk = 0; kk < 2; kk++)
    qf[kk] = *(const bf16x8*)(qp + (size_t)(q0w + lc) * DK + kk * 32 + quad * 8);

  const f32x4 fz = {0.f, 0.f, 0.f, 0.f};
  f32x4 acc_o[4];
#pragma unroll
  for (int ct = 0; ct < 4; ct++) acc_o[ct] = fz;
  float m_i[4], l_i[4];
#pragma unroll
  for (int r = 0; r < 4; r++) { m_i[r] = -__builtin_inff(); l_i[r] = 0.f; }

  const int jstart = (q0w >= SLEN + SEQ) ? 2 : 0;
  const int jend   = q0w >> 6;
  const int pdiag  = (q0w >> 4) & 3;    // diagonal sub-tile index

  for (int j = jstart; j <= jend; ++j) {
    const int c0 = j * 64;
    const bool diag = (j == jend);
    const int ctmax = diag ? pdiag : 3;

    f32x4 s[4];
#pragma unroll
    for (int ct = 0; ct < 4; ct++) s[ct] = fz;
#pragma unroll
    for (int ct = 0; ct < 4; ct++) {
      if (ct > ctmax) break;
#pragma unroll
      for (int kk = 0; kk < 2; kk++) {
        bf16x8 kf = *(const bf16x8*)(kp + (size_t)(c0 + ct * 16 + lc) * DK + kk * 32 + quad * 8);
        s[ct] = __builtin_amdgcn_mfma_f32_16x16x32_bf16(qf[kk], kf, s[ct], 0, 0, 0);
      }
    }

    // online softmax (q pre-scaled); C layout: row=quad*4+r, col=ct*16+lc
#pragma unroll
    for (int r = 0; r < 4; r++) {
      const int R = q0w + quad * 4 + r;
      float p[4];
      float mx = -__builtin_inff();
#pragma unroll
      for (int ct = 0; ct < 4; ct++) {
        float val = s[ct][r];
        if (diag && (c0 + ct * 16 + lc) > R) val = -__builtin_inff();
        p[ct] = val;
        mx = fmaxf(mx, val);
      }
#pragma unroll
      for (int off = 1; off < 16; off <<= 1) mx = fmaxf(mx, __shfl_xor(mx, off, 64));
      float mnew  = fmaxf(m_i[r], mx);
      float alpha = __expf(m_i[r] - mnew);
      float rs = 0.f;
#pragma unroll
      for (int ct = 0; ct < 4; ct++) {
        float pe = __expf(p[ct] - mnew);
        p[ct] = pe;
        rs += pe;
      }
#pragma unroll
      for (int off = 1; off < 16; off <<= 1) rs += __shfl_xor(rs, off, 64);
      l_i[r] = l_i[r] * alpha + rs;
      m_i[r] = mnew;
#pragma unroll
      for (int ct = 0; ct < 4; ct++) acc_o[ct][r] *= alpha;
#pragma unroll
      for (int ct = 0; ct < 4; ct++) {
        int col = ct * 16 + lc;
        int mrow = quad * 4 + r;
        int slotc = (col >> 3) ^ (mrow & 7);
        Ps[wave][mrow * 64 + slotc * 8 + (col & 7)] = (__bf16)p[ct];
      }
    }

    // O += P V   (A = P from wave-local LDS, B = V^T direct from global)
#pragma unroll
    for (int kk = 0; kk < 2; kk++) {
      int slot = lc * 8 + ((kk * 4 + quad) ^ (lc & 7));
      bf16x8 pa = *(const bf16x8*)(&Ps[wave][0] + slot * 8);
#pragma unroll
      for (int ct = 0; ct < 4; ct++) {
        bf16x8 vf = *(const bf16x8*)(vp + (size_t)(ct * 16 + lc) * T_TOT + c0 + kk * 32 + quad * 8);
        acc_o[ct] = __builtin_amdgcn_mfma_f32_16x16x32_bf16(pa, vf, acc_o[ct], 0, 0, 0);
      }
    }
  }

  // epilogue
#pragma unroll
  for (int r = 0; r < 4; r++) {
    const int R = q0w + quad * 4 + r;
    float invl = 1.0f / l_i[r];
#pragma unroll
    for (int ct = 0; ct < 4; ct++)
      out[((size_t)h * T_TOT + R) * DK + ct * 16 + lc] = acc_o[ct][r] * invl;
  }
}

extern "C" void kernel_launch(void* const* d_in, const int* in_sizes, int n_in,
                              void* d_out, int out_size, void* d_ws, size_t ws_size,
                              hipStream_t stream) {
  const float* x    = (const float*)d_in[0];
  const float* Wq   = (const float*)d_in[1];
  const float* Wk   = (const float*)d_in[2];
  const float* Wv   = (const float*)d_in[3];
  const float* Wqs  = (const float*)d_in[4];
  const float* Wks  = (const float*)d_in[5];
  const float* Wvs  = (const float*)d_in[6];
  const float* scal = (const float*)d_in[7];
  float* out = (float*)d_out;

  char* ws = (char*)d_ws;
  size_t off = 0;
  __bf16* xb  = (__bf16*)(ws + off); off += (size_t)T_TOT * DDIM * 2;          // 4.72 MB
  __bf16* Wt  = (__bf16*)(ws + off); off += (size_t)6 * NH * DK * DDIM * 2;    // 12.58 MB
  __bf16* qkv = (__bf16*)(ws + off); off += (size_t)2 * NH * T_TOT * DK * 2;   // 9.44 MB (q,k)
  __bf16* vt  = (__bf16*)(ws + off);                                           // 4.72 MB

  convert_kernel<<<2112, 256, 0, stream>>>(x, Wq, Wk, Wv, Wqs, Wks, Wvs, xb, Wt);
  proj_kernel<<<dim3(3, 18, NH), 256, 0, stream>>>(xb, Wt, scal, qkv, vt);
  attn_kernel<<<dim3(576), 256, 0, stream>>>(qkv, vt, out);
}

// Round 3
// 200.306 us; speedup vs baseline: 1.4670x; 1.2164x over previous
//
#include <hip/hip_runtime.h>
#include <hip/hip_bf16.h>

#define T_TOT 2304
#define DDIM  1024
#define NH    16
#define DK    64
#define SLEN  128
#define SEQ   2048

typedef __bf16 bf16x8 __attribute__((ext_vector_type(8)));
typedef __bf16 bf16x4 __attribute__((ext_vector_type(4)));
typedef float  f32x4  __attribute__((ext_vector_type(4)));

__device__ __forceinline__ void async_copy16(const void* gsrc, void* ldst) {
  __builtin_amdgcn_global_load_lds(
      (const __attribute__((address_space(1))) void*)gsrc,
      (__attribute__((address_space(3))) void*)ldst, 16, 0, 0);
}

// ---------------- convert: x -> bf16 (vectorized); W[h][d][n] -> Wt[m][h][n][d] via LDS transpose
__global__ __launch_bounds__(256) void convert_kernel(
    const float* __restrict__ x,
    const float* __restrict__ Wq, const float* __restrict__ Wk,
    const float* __restrict__ Wv, const float* __restrict__ Wqs,
    const float* __restrict__ Wks, const float* __restrict__ Wvs,
    __bf16* __restrict__ xb, __bf16* __restrict__ Wt) {
  const int b = blockIdx.x;
  const int tid = threadIdx.x;
  if (b < 576) {
    const float4* xin = (const float4*)x;
#pragma unroll
    for (int it = 0; it < 4; ++it) {
      int idx4 = b * 1024 + it * 256 + tid;
      float4 v = xin[idx4];
      bf16x4 o;
      o[0] = (__bf16)v.x; o[1] = (__bf16)v.y; o[2] = (__bf16)v.z; o[3] = (__bf16)v.w;
      *(bf16x4*)(xb + (size_t)idx4 * 4) = o;
    }
    return;
  }
  __shared__ float tile[64 * 65];
  const int wb = b - 576;
  const int m  = wb >> 8;
  const int rem = wb & 255;
  const int h  = rem >> 4;
  const int dt = rem & 15;
  const int d0 = dt * 64;
  const float* Wsrc = (m == 0 ? Wq : m == 1 ? Wk : m == 2 ? Wv
                      : m == 3 ? Wqs : m == 4 ? Wks : Wvs) + (size_t)h * (DDIM * DK);
#pragma unroll
  for (int rr = 0; rr < 4; ++rr) {
    int drow = rr * 16 + (tid >> 4);
    int nc   = (tid & 15) * 4;
    float4 v = *(const float4*)(Wsrc + (size_t)(d0 + drow) * DK + nc);
    tile[(nc + 0) * 65 + drow] = v.x;
    tile[(nc + 1) * 65 + drow] = v.y;
    tile[(nc + 2) * 65 + drow] = v.z;
    tile[(nc + 3) * 65 + drow] = v.w;
  }
  __syncthreads();
  {
    int n  = tid >> 2;
    int rg = (tid & 3) * 16;
    __bf16* dst = Wt + (((size_t)(m * NH + h)) * DK + n) * DDIM + d0 + rg;
    bf16x8 o0, o1;
#pragma unroll
    for (int e = 0; e < 8; e++) o0[e] = (__bf16)tile[n * 65 + rg + e];
#pragma unroll
    for (int e = 0; e < 8; e++) o1[e] = (__bf16)tile[n * 65 + rg + 8 + e];
    *(bf16x8*)dst = o0;
    *(bf16x8*)(dst + 8) = o1;
  }
}

// ---------------- projection + l2norm (+q prescale, v transposed store)
__global__ __launch_bounds__(256) void proj_kernel(
    const __bf16* __restrict__ xb, const __bf16* __restrict__ Wt,
    const float* __restrict__ scal,
    __bf16* __restrict__ qkv, __bf16* __restrict__ vt) {
  const int which = blockIdx.x;
  const int rt    = blockIdx.y;
  const int h     = blockIdx.z;
  const int r0    = rt * 128;
  const int m     = (rt == 0 || rt == 17) ? which + 3 : which;

  __shared__ __bf16 Xs[128 * 64];
  __shared__ __bf16 Wsh[64 * 64];

  const int tid  = threadIdx.x;
  const int wave = tid >> 6, lane = tid & 63;
  const int quad = lane >> 4, lc = lane & 15;

  const __bf16* Wbase = Wt + ((size_t)(m * NH + h)) * (DK * DDIM);

  const f32x4 fz = {0.f, 0.f, 0.f, 0.f};
  f32x4 acc[2][4];
#pragma unroll
  for (int i = 0; i < 2; i++)
#pragma unroll
    for (int j = 0; j < 4; j++) acc[i][j] = fz;

  for (int k0 = 0; k0 < DDIM; k0 += 64) {
#pragma unroll
    for (int it = 0; it < 4; ++it) {
      int L = it * 256 + tid;
      int row = L >> 3, c = (L & 7) ^ ((L >> 3) & 7);
      async_copy16(xb + (size_t)(r0 + row) * DDIM + k0 + c * 8,
                   (char*)Xs + (size_t)(it * 256 + wave * 64) * 16);
    }
#pragma unroll
    for (int it = 0; it < 2; ++it) {
      int L = it * 256 + tid;
      int row = L >> 3, c = (L & 7) ^ ((L >> 3) & 7);
      async_copy16(Wbase + (size_t)row * DDIM + k0 + c * 8,
                   (char*)Wsh + (size_t)(it * 256 + wave * 64) * 16);
    }
    __syncthreads();
    bf16x8 afr[2][2], bfr[2][4];
#pragma unroll
    for (int kk = 0; kk < 2; kk++) {
#pragma unroll
      for (int i = 0; i < 2; i++) {
        int row = wave * 32 + i * 16 + lc;
        int ch  = (kk * 4 + quad) ^ (row & 7);
        afr[kk][i] = *(const bf16x8*)(Xs + (row * 8 + ch) * 8);
      }
#pragma unroll
      for (int j = 0; j < 4; j++) {
        int row = j * 16 + lc;
        int ch  = (kk * 4 + quad) ^ (row & 7);
        bfr[kk][j] = *(const bf16x8*)(Wsh + (row * 8 + ch) * 8);
      }
    }
#pragma unroll
    for (int kk = 0; kk < 2; kk++)
#pragma unroll
      for (int i = 0; i < 2; i++)
#pragma unroll
        for (int j = 0; j < 4; j++)
          acc[i][j] = __builtin_amdgcn_mfma_f32_16x16x32_bf16(afr[kk][i], bfr[kk][j], acc[i][j], 0, 0, 0);
    __syncthreads();
  }

  float inv4[2][4];
  const float qscale = (which == 0) ? scal[h] : 1.0f;
#pragma unroll
  for (int i = 0; i < 2; i++) {
#pragma unroll
    for (int r = 0; r < 4; r++) {
      float s = 0.f;
#pragma unroll
      for (int j = 0; j < 4; j++) { float v = acc[i][j][r]; s += v * v; }
#pragma unroll
      for (int off = 1; off < 16; off <<= 1) s += __shfl_xor(s, off, 64);
      inv4[i][r] = qscale / fmaxf(sqrtf(s), 1e-12f);
    }
  }
  if (which == 2) {
    __bf16* vtp = vt + (size_t)h * (DK * T_TOT);
#pragma unroll
    for (int i = 0; i < 2; i++) {
      int rowbase = r0 + wave * 32 + i * 16 + quad * 4;
#pragma unroll
      for (int j = 0; j < 4; j++) {
        bf16x4 o;
#pragma unroll
        for (int r = 0; r < 4; r++) o[r] = (__bf16)(acc[i][j][r] * inv4[i][r]);
        *(bf16x4*)(vtp + (size_t)(j * 16 + lc) * T_TOT + rowbase) = o;
      }
    }
  } else {
    __bf16* outp = qkv + ((size_t)(which * NH + h)) * ((size_t)T_TOT * DK);
#pragma unroll
    for (int i = 0; i < 2; i++)
#pragma unroll
      for (int r = 0; r < 4; r++) {
        int row = r0 + wave * 32 + i * 16 + quad * 4 + r;
#pragma unroll
        for (int j = 0; j < 4; j++)
          outp[(size_t)row * DK + j * 16 + lc] = (__bf16)(acc[i][j][r] * inv4[i][r]);
      }
  }
}

// ---------------- flash attention v3: S^T structure, kv-split across wave pair
// Block = 128 threads = 2 waves handling one 16-row q-tile (kv range split in half).
__global__ __launch_bounds__(128, 4) void attn_kernel(
    const __bf16* __restrict__ qkv, const __bf16* __restrict__ vt,
    float* __restrict__ out) {
  const int b    = blockIdx.x;          // 0..2303
  const int h    = b & 15;
  const int qt   = 143 - (b >> 4);      // big work dispatched first
  const int q0w  = qt * 16;
  const int tid  = threadIdx.x;
  const int wave = tid >> 6, lane = tid & 63;
  const int quad = lane >> 4, lc = lane & 15;

  const __bf16* qp = qkv + ((size_t)h) * ((size_t)T_TOT * DK);
  const __bf16* kp = qkv + ((size_t)(NH + h)) * ((size_t)T_TOT * DK);
  const __bf16* vp = vt + (size_t)h * (DK * T_TOT);

  __shared__ __bf16 Ps[2][16 * 64];     // per-wave P tile [q][kv] (swizzled 16B chunks)
  __shared__ float  OL[1024];           // wave1's O^T for merge
  __shared__ float  mL[16], lL[16];

  // Q B-frag (persistent): Q[q=lc][d=kk*32+quad*8+e]
  bf16x8 qf[2];
#pragma unroll
  for (int kk = 0; kk < 2; kk++)
    qf[kk] = *(const bf16x8*)(qp + (size_t)(q0w + lc) * DK + kk * 32 + quad * 8);

  const f32x4 fz = {0.f, 0.f, 0.f, 0.f};
  f32x4 acc_o[4];                       // O^T: d = ct*16+quad*4+r, q = lc
#pragma unroll
  for (int ct = 0; ct < 4; ct++) acc_o[ct] = fz;
  float m_i = -__builtin_inff(), l_i = 0.f;

  const int jstart = (q0w >= SLEN + SEQ) ? 2 : 0;
  const int jend   = q0w >> 6;          // diagonal-containing 64-kv tile
  const int nt     = jend - jstart + 1;
  const int jmid   = jstart + (nt >> 1);
  const int j0     = wave ? jmid : jstart;
  const int j1     = wave ? jend : jmid - 1;
  const int pdiag  = (q0w >> 4) & 3;

  for (int j = j0; j <= j1; ++j) {
    const int c0 = j * 64;
    const bool diag = (j == jend);
    const int ctmax = diag ? pdiag : 3;

    // V^T A-frags issued early (used after softmax)
    bf16x8 vA[2][4];
#pragma unroll
    for (int ct = 0; ct < 4; ct++)
#pragma unroll
      for (int kk = 0; kk < 2; kk++)
        vA[kk][ct] = *(const bf16x8*)(vp + (size_t)(ct * 16 + lc) * T_TOT + c0 + kk * 32 + quad * 8);

    // S^T = K Q^T : C[kv_local=quad*4+r][q=lc]
    f32x4 s[4];
#pragma unroll
    for (int ct = 0; ct < 4; ct++) s[ct] = fz;
#pragma unroll
    for (int ct = 0; ct < 4; ct++) {
      if (ct <= ctmax) {
#pragma unroll
        for (int kk = 0; kk < 2; kk++) {
          bf16x8 kA = *(const bf16x8*)(kp + (size_t)(c0 + ct * 16 + lc) * DK + kk * 32 + quad * 8);
          s[ct] = __builtin_amdgcn_mfma_f32_16x16x32_bf16(kA, qf[kk], s[ct], 0, 0, 0);
        }
      }
    }

    // softmax over kv (regs tree + 2 cross-quad shuffles); q pre-scaled
    float p[4][4];
    float mx = -__builtin_inff();
#pragma unroll
    for (int ct = 0; ct < 4; ct++)
#pragma unroll
      for (int r = 0; r < 4; r++) {
        float v = s[ct][r];
        if (diag && (c0 + ct * 16 + quad * 4 + r) > (q0w + lc)) v = -__builtin_inff();
        p[ct][r] = v;
        mx = fmaxf(mx, v);
      }
    mx = fmaxf(mx, __shfl_xor(mx, 16, 64));
    mx = fmaxf(mx, __shfl_xor(mx, 32, 64));
    float mnew  = fmaxf(m_i, mx);
    float alpha = __expf(m_i - mnew);
    float rs = 0.f;
#pragma unroll
    for (int ct = 0; ct < 4; ct++)
#pragma unroll
      for (int r = 0; r < 4; r++) {
        float pe = __expf(p[ct][r] - mnew);
        p[ct][r] = pe;
        rs += pe;
      }
    rs += __shfl_xor(rs, 16, 64);
    rs += __shfl_xor(rs, 32, 64);
    l_i = l_i * alpha + rs;
    m_i = mnew;
#pragma unroll
    for (int ct = 0; ct < 4; ct++)
#pragma unroll
      for (int r = 0; r < 4; r++) acc_o[ct][r] *= alpha;

    // write P to wave-local LDS: [q=lc][kv], 16B-chunk swizzle cc' = cc ^ (lc&7)
#pragma unroll
    for (int ct = 0; ct < 4; ct++) {
      bf16x4 pb;
#pragma unroll
      for (int r = 0; r < 4; r++) pb[r] = (__bf16)p[ct][r];
      int cc = ct * 2 + (quad >> 1);
      int el = lc * 64 + ((cc ^ (lc & 7)) * 8) + (quad & 1) * 4;
      *(bf16x4*)(&Ps[wave][el]) = pb;
    }

    // O^T += V^T P^T : A = V^T (global), B = P (LDS)
#pragma unroll
    for (int kk = 0; kk < 2; kk++) {
      int cc = kk * 4 + quad;
      int el = lc * 64 + ((cc ^ (lc & 7)) * 8);
      bf16x8 pB = *(const bf16x8*)(&Ps[wave][el]);
#pragma unroll
      for (int ct = 0; ct < 4; ct++)
        acc_o[ct] = __builtin_amdgcn_mfma_f32_16x16x32_bf16(vA[kk][ct], pB, acc_o[ct], 0, 0, 0);
    }
  }

  // merge halves: wave1 publishes, wave0 combines + stores
  if (wave == 1) {
#pragma unroll
    for (int ct = 0; ct < 4; ct++)
      *(f32x4*)(&OL[((ct * 4 + quad) * 16 + lc) * 4]) = acc_o[ct];
    if (quad == 0) { mL[lc] = m_i; lL[lc] = l_i; }
  }
  __syncthreads();
  if (wave == 0) {
    float m1 = mL[lc], l1 = lL[lc];
    float M  = fmaxf(m_i, m1);
    float a0 = __expf(m_i - M);
    float a1 = __expf(m1 - M);
    float invl = 1.0f / (a0 * l_i + a1 * l1);
#pragma unroll
    for (int ct = 0; ct < 4; ct++) {
      f32x4 o1 = *(const f32x4*)(&OL[((ct * 4 + quad) * 16 + lc) * 4]);
      f32x4 o;
#pragma unroll
      for (int r = 0; r < 4; r++) o[r] = (a0 * acc_o[ct][r] + a1 * o1[r]) * invl;
      *(f32x4*)(&out[((size_t)h * T_TOT + q0w + lc) * DK + ct * 16 + quad * 4]) = o;
    }
  }
}

extern "C" void kernel_launch(void* const* d_in, const int* in_sizes, int n_in,
                              void* d_out, int out_size, void* d_ws, size_t ws_size,
                              hipStream_t stream) {
  const float* x    = (const float*)d_in[0];
  const float* Wq   = (const float*)d_in[1];
  const float* Wk   = (const float*)d_in[2];
  const float* Wv   = (const float*)d_in[3];
  const float* Wqs  = (const float*)d_in[4];
  const float* Wks  = (const float*)d_in[5];
  const float* Wvs  = (const float*)d_in[6];
  const float* scal = (const float*)d_in[7];
  float* out = (float*)d_out;

  char* ws = (char*)d_ws;
  size_t off = 0;
  __bf16* xb  = (__bf16*)(ws + off); off += (size_t)T_TOT * DDIM * 2;
  __bf16* Wt  = (__bf16*)(ws + off); off += (size_t)6 * NH * DK * DDIM * 2;
  __bf16* qkv = (__bf16*)(ws + off); off += (size_t)2 * NH * T_TOT * DK * 2;
  __bf16* vt  = (__bf16*)(ws + off);

  convert_kernel<<<2112, 256, 0, stream>>>(x, Wq, Wk, Wv, Wqs, Wks, Wvs, xb, Wt);
  proj_kernel<<<dim3(3, 18, NH), 256, 0, stream>>>(xb, Wt, scal, qkv, vt);
  attn_kernel<<<dim3(2304), 128, 0, stream>>>(qkv, vt, out);
}

// Round 4
// 197.662 us; speedup vs baseline: 1.4867x; 1.0134x over previous
//
#include <hip/hip_runtime.h>
#include <hip/hip_bf16.h>

#define T_TOT 2304
#define DDIM  1024
#define NH    16
#define DK    64
#define SLEN  128
#define SEQ   2048

typedef __bf16 bf16x8 __attribute__((ext_vector_type(8)));
typedef __bf16 bf16x4 __attribute__((ext_vector_type(4)));
typedef float  f32x4  __attribute__((ext_vector_type(4)));

__device__ __forceinline__ void async_copy16(const void* gsrc, void* ldst) {
  __builtin_amdgcn_global_load_lds(
      (const __attribute__((address_space(1))) void*)gsrc,
      (__attribute__((address_space(3))) void*)ldst, 16, 0, 0);
}

// ---------------- convert: x -> bf16 (vectorized); W[h][d][n] -> Wt[m][h][n][d] via LDS transpose
__global__ __launch_bounds__(256) void convert_kernel(
    const float* __restrict__ x,
    const float* __restrict__ Wq, const float* __restrict__ Wk,
    const float* __restrict__ Wv, const float* __restrict__ Wqs,
    const float* __restrict__ Wks, const float* __restrict__ Wvs,
    __bf16* __restrict__ xb, __bf16* __restrict__ Wt) {
  const int b = blockIdx.x;
  const int tid = threadIdx.x;
  if (b < 576) {
    const float4* xin = (const float4*)x;
#pragma unroll
    for (int it = 0; it < 4; ++it) {
      int idx4 = b * 1024 + it * 256 + tid;
      float4 v = xin[idx4];
      bf16x4 o;
      o[0] = (__bf16)v.x; o[1] = (__bf16)v.y; o[2] = (__bf16)v.z; o[3] = (__bf16)v.w;
      *(bf16x4*)(xb + (size_t)idx4 * 4) = o;
    }
    return;
  }
  __shared__ float tile[64 * 65];
  const int wb = b - 576;
  const int m  = wb >> 8;
  const int rem = wb & 255;
  const int h  = rem >> 4;
  const int dt = rem & 15;
  const int d0 = dt * 64;
  const float* Wsrc = (m == 0 ? Wq : m == 1 ? Wk : m == 2 ? Wv
                      : m == 3 ? Wqs : m == 4 ? Wks : Wvs) + (size_t)h * (DDIM * DK);
#pragma unroll
  for (int rr = 0; rr < 4; ++rr) {
    int drow = rr * 16 + (tid >> 4);
    int nc   = (tid & 15) * 4;
    float4 v = *(const float4*)(Wsrc + (size_t)(d0 + drow) * DK + nc);
    tile[(nc + 0) * 65 + drow] = v.x;
    tile[(nc + 1) * 65 + drow] = v.y;
    tile[(nc + 2) * 65 + drow] = v.z;
    tile[(nc + 3) * 65 + drow] = v.w;
  }
  __syncthreads();
  {
    int n  = tid >> 2;
    int rg = (tid & 3) * 16;
    __bf16* dst = Wt + (((size_t)(m * NH + h)) * DK + n) * DDIM + d0 + rg;
    bf16x8 o0, o1;
#pragma unroll
    for (int e = 0; e < 8; e++) o0[e] = (__bf16)tile[n * 65 + rg + e];
#pragma unroll
    for (int e = 0; e < 8; e++) o1[e] = (__bf16)tile[n * 65 + rg + 8 + e];
    *(bf16x8*)dst = o0;
    *(bf16x8*)(dst + 8) = o1;
  }
}

// ---------------- projection + l2norm, BK=128 (8 iters, 32 MFMA per barrier-pair)
__global__ __launch_bounds__(256) void proj_kernel(
    const __bf16* __restrict__ xb, const __bf16* __restrict__ Wt,
    const float* __restrict__ scal,
    __bf16* __restrict__ qkv, __bf16* __restrict__ vt) {
  const int which = blockIdx.x;
  const int rt    = blockIdx.y;
  const int h     = blockIdx.z;
  const int r0    = rt * 128;
  const int m     = (rt == 0 || rt == 17) ? which + 3 : which;

  __shared__ __bf16 Xs[128 * 128];   // 32 KB
  __shared__ __bf16 Wsh[64 * 128];   // 16 KB

  const int tid  = threadIdx.x;
  const int wave = tid >> 6, lane = tid & 63;
  const int quad = lane >> 4, lc = lane & 15;

  const __bf16* Wbase = Wt + ((size_t)(m * NH + h)) * (DK * DDIM);

  const f32x4 fz = {0.f, 0.f, 0.f, 0.f};
  f32x4 acc[2][4];
#pragma unroll
  for (int i = 0; i < 2; i++)
#pragma unroll
    for (int j = 0; j < 4; j++) acc[i][j] = fz;

  for (int k0 = 0; k0 < DDIM; k0 += 128) {
    // X tile 128x128: 2048 chunks (16 per row), swizzle c' = c ^ (row&15)
#pragma unroll
    for (int it = 0; it < 8; ++it) {
      int L = it * 256 + tid;
      int row = L >> 4, c = (L & 15) ^ ((L >> 4) & 15);
      async_copy16(xb + (size_t)(r0 + row) * DDIM + k0 + c * 8,
                   (char*)Xs + (size_t)(it * 256 + wave * 64) * 16);
    }
    // W tile 64x128: 1024 chunks
#pragma unroll
    for (int it = 0; it < 4; ++it) {
      int L = it * 256 + tid;
      int row = L >> 4, c = (L & 15) ^ ((L >> 4) & 15);
      async_copy16(Wbase + (size_t)row * DDIM + k0 + c * 8,
                   (char*)Wsh + (size_t)(it * 256 + wave * 64) * 16);
    }
    __syncthreads();
#pragma unroll
    for (int kk = 0; kk < 4; kk++) {
      bf16x8 afr[2], bfr[4];
#pragma unroll
      for (int i = 0; i < 2; i++) {
        int row = wave * 32 + i * 16 + lc;
        int ch  = (kk * 4 + quad) ^ (row & 15);
        afr[i] = *(const bf16x8*)(Xs + (row * 16 + ch) * 8);
      }
#pragma unroll
      for (int j = 0; j < 4; j++) {
        int row = j * 16 + lc;
        int ch  = (kk * 4 + quad) ^ (row & 15);
        bfr[j] = *(const bf16x8*)(Wsh + (row * 16 + ch) * 8);
      }
#pragma unroll
      for (int i = 0; i < 2; i++)
#pragma unroll
        for (int j = 0; j < 4; j++)
          acc[i][j] = __builtin_amdgcn_mfma_f32_16x16x32_bf16(afr[i], bfr[j], acc[i][j], 0, 0, 0);
    }
    __syncthreads();
  }

  float inv4[2][4];
  const float qscale = (which == 0) ? scal[h] : 1.0f;
#pragma unroll
  for (int i = 0; i < 2; i++) {
#pragma unroll
    for (int r = 0; r < 4; r++) {
      float s = 0.f;
#pragma unroll
      for (int j = 0; j < 4; j++) { float v = acc[i][j][r]; s += v * v; }
#pragma unroll
      for (int off = 1; off < 16; off <<= 1) s += __shfl_xor(s, off, 64);
      inv4[i][r] = qscale / fmaxf(sqrtf(s), 1e-12f);
    }
  }
  if (which == 2) {
    __bf16* vtp = vt + (size_t)h * (DK * T_TOT);
#pragma unroll
    for (int i = 0; i < 2; i++) {
      int rowbase = r0 + wave * 32 + i * 16 + quad * 4;
#pragma unroll
      for (int j = 0; j < 4; j++) {
        bf16x4 o;
#pragma unroll
        for (int r = 0; r < 4; r++) o[r] = (__bf16)(acc[i][j][r] * inv4[i][r]);
        *(bf16x4*)(vtp + (size_t)(j * 16 + lc) * T_TOT + rowbase) = o;
      }
    }
  } else {
    __bf16* outp = qkv + ((size_t)(which * NH + h)) * ((size_t)T_TOT * DK);
#pragma unroll
    for (int i = 0; i < 2; i++)
#pragma unroll
      for (int r = 0; r < 4; r++) {
        int row = r0 + wave * 32 + i * 16 + quad * 4 + r;
#pragma unroll
        for (int j = 0; j < 4; j++)
          outp[(size_t)row * DK + j * 16 + lc] = (__bf16)(acc[i][j][r] * inv4[i][r]);
      }
  }
}

// ---------------- flash attention v4: S^T, BN=128, 4-way kv split per q-tile
// Block = 256 threads = 4 waves, one 16-row q-tile; kv 128-units split contiguously.
__global__ __launch_bounds__(256) void attn_kernel(
    const __bf16* __restrict__ qkv, const __bf16* __restrict__ vt,
    float* __restrict__ out) {
  const int b    = blockIdx.x;          // 0..2303
  const int h    = b & 15;
  const int qt   = 143 - (b >> 4);      // big work first
  const int q0w  = qt * 16;
  const int tid  = threadIdx.x;
  const int wave = tid >> 6, lane = tid & 63;
  const int quad = lane >> 4, lc = lane & 15;

  const __bf16* qp = qkv + ((size_t)h) * ((size_t)T_TOT * DK);
  const __bf16* kp = qkv + ((size_t)(NH + h)) * ((size_t)T_TOT * DK);
  const __bf16* vp = vt + (size_t)h * (DK * T_TOT);

  __shared__ __bf16 Ps[4][16 * 128];    // per-wave P tile [q][kv], swizzled 16B chunks
  __shared__ float  OL[3][1024];        // waves 1..3 O^T for merge
  __shared__ float  mlL[3][2][16];

  // Q B-frag (persistent)
  bf16x8 qf[2];
#pragma unroll
  for (int kk = 0; kk < 2; kk++)
    qf[kk] = *(const bf16x8*)(qp + (size_t)(q0w + lc) * DK + kk * 32 + quad * 8);

  const f32x4 fz = {0.f, 0.f, 0.f, 0.f};
  f32x4 acc_o[4];                       // O^T: d = ct*16+quad*4+r, q = lc
#pragma unroll
  for (int ct = 0; ct < 4; ct++) acc_o[ct] = fz;
  float m_i = -__builtin_inff(), l_i = 0.f;

  const int ustart = (q0w >= SLEN + SEQ) ? 1 : 0;
  const int uend   = q0w >> 7;
  const int nu     = uend - ustart + 1;
  const int b0     = ustart + ((nu * wave) >> 2);
  const int b1     = ustart + ((nu * (wave + 1)) >> 2);
  const int ctdiag = (q0w >> 4) & 7;

  for (int u = b0; u < b1; ++u) {
    const int c0 = u * 128;
    const bool diag = (u == uend);
    const int ctmax = diag ? ctdiag : 7;

    // S^T = K Q^T over 128 kv: C[kv=ct*16+quad*4+r][q=lc]
    f32x4 s[8];
#pragma unroll
    for (int ct = 0; ct < 8; ct++) s[ct] = fz;
#pragma unroll
    for (int ct = 0; ct < 8; ct++) {
      if (ct <= ctmax) {
#pragma unroll
        for (int kk = 0; kk < 2; kk++) {
          bf16x8 kA = *(const bf16x8*)(kp + (size_t)(c0 + ct * 16 + lc) * DK + kk * 32 + quad * 8);
          s[ct] = __builtin_amdgcn_mfma_f32_16x16x32_bf16(kA, qf[kk], s[ct], 0, 0, 0);
        }
      }
    }

    // softmax over 128 kv (in-place in s), 2 cross-quad shuffles total per reduce
    float mx = -__builtin_inff();
#pragma unroll
    for (int ct = 0; ct < 8; ct++)
#pragma unroll
      for (int r = 0; r < 4; r++) {
        float v = s[ct][r];
        if (diag && (c0 + ct * 16 + quad * 4 + r) > (q0w + lc)) v = -__builtin_inff();
        s[ct][r] = v;
        mx = fmaxf(mx, v);
      }
    mx = fmaxf(mx, __shfl_xor(mx, 16, 64));
    mx = fmaxf(mx, __shfl_xor(mx, 32, 64));
    float mnew  = fmaxf(m_i, mx);
    float alpha = __expf(m_i - mnew);
    float rs = 0.f;
#pragma unroll
    for (int ct = 0; ct < 8; ct++)
#pragma unroll
      for (int r = 0; r < 4; r++) {
        float pe = __expf(s[ct][r] - mnew);
        s[ct][r] = pe;
        rs += pe;
      }
    rs += __shfl_xor(rs, 16, 64);
    rs += __shfl_xor(rs, 32, 64);
    l_i = l_i * alpha + rs;
    m_i = mnew;
#pragma unroll
    for (int ct = 0; ct < 4; ct++)
#pragma unroll
      for (int r = 0; r < 4; r++) acc_o[ct][r] *= alpha;

    // write P to wave-local LDS: [q=lc][kv], chunk swizzle cc' = cc ^ lc (16 chunks/row)
#pragma unroll
    for (int ct = 0; ct < 8; ct++) {
      bf16x4 pb;
#pragma unroll
      for (int r = 0; r < 4; r++) pb[r] = (__bf16)s[ct][r];
      int cc = ct * 2 + (quad >> 1);
      int el = lc * 128 + ((cc ^ lc) * 8) + (quad & 1) * 4;
      *(bf16x4*)(&Ps[wave][el]) = pb;
    }

    // O^T += V^T P^T : A = V^T (global), B = P (LDS)
    const int kqmax = diag ? (ctmax >> 1) : 3;
#pragma unroll
    for (int kq = 0; kq < 4; kq++) {
      if (kq <= kqmax) {
        int cc = kq * 4 + quad;
        bf16x8 pB = *(const bf16x8*)(&Ps[wave][lc * 128 + ((cc ^ lc) * 8)]);
#pragma unroll
        for (int ct = 0; ct < 4; ct++) {
          bf16x8 vA = *(const bf16x8*)(vp + (size_t)(ct * 16 + lc) * T_TOT + c0 + kq * 32 + quad * 8);
          acc_o[ct] = __builtin_amdgcn_mfma_f32_16x16x32_bf16(vA, pB, acc_o[ct], 0, 0, 0);
        }
      }
    }
  }

  // merge 4 partial results (log-sum-exp combine)
  if (wave != 0) {
#pragma unroll
    for (int ct = 0; ct < 4; ct++)
      *(f32x4*)(&OL[wave - 1][((ct * 4 + quad) * 16 + lc) * 4]) = acc_o[ct];
    if (quad == 0) { mlL[wave - 1][0][lc] = m_i; mlL[wave - 1][1][lc] = l_i; }
  }
  __syncthreads();
  if (wave == 0) {
    float mw[3], lw[3];
#pragma unroll
    for (int w = 0; w < 3; w++) { mw[w] = mlL[w][0][lc]; lw[w] = mlL[w][1][lc]; }
    float M = m_i;
#pragma unroll
    for (int w = 0; w < 3; w++) M = fmaxf(M, mw[w]);
    float a0 = __expf(m_i - M);
    float aw[3];
    float Lt = a0 * l_i;
#pragma unroll
    for (int w = 0; w < 3; w++) { aw[w] = __expf(mw[w] - M); Lt += aw[w] * lw[w]; }
    float invl = 1.0f / Lt;
#pragma unroll
    for (int ct = 0; ct < 4; ct++) {
      f32x4 o;
#pragma unroll
      for (int r = 0; r < 4; r++) o[r] = a0 * acc_o[ct][r];
#pragma unroll
      for (int w = 0; w < 3; w++) {
        f32x4 ow = *(const f32x4*)(&OL[w][((ct * 4 + quad) * 16 + lc) * 4]);
#pragma unroll
        for (int r = 0; r < 4; r++) o[r] += aw[w] * ow[r];
      }
#pragma unroll
      for (int r = 0; r < 4; r++) o[r] *= invl;
      *(f32x4*)(&out[((size_t)h * T_TOT + q0w + lc) * DK + ct * 16 + quad * 4]) = o;
    }
  }
}

extern "C" void kernel_launch(void* const* d_in, const int* in_sizes, int n_in,
                              void* d_out, int out_size, void* d_ws, size_t ws_size,
                              hipStream_t stream) {
  const float* x    = (const float*)d_in[0];
  const float* Wq   = (const float*)d_in[1];
  const float* Wk   = (const float*)d_in[2];
  const float* Wv   = (const float*)d_in[3];
  const float* Wqs  = (const float*)d_in[4];
  const float* Wks  = (const float*)d_in[5];
  const float* Wvs  = (const float*)d_in[6];
  const float* scal = (const float*)d_in[7];
  float* out = (float*)d_out;

  char* ws = (char*)d_ws;
  size_t off = 0;
  __bf16* xb  = (__bf16*)(ws + off); off += (size_t)T_TOT * DDIM * 2;
  __bf16* Wt  = (__bf16*)(ws + off); off += (size_t)6 * NH * DK * DDIM * 2;
  __bf16* qkv = (__bf16*)(ws + off); off += (size_t)2 * NH * T_TOT * DK * 2;
  __bf16* vt  = (__bf16*)(ws + off);

  convert_kernel<<<2112, 256, 0, stream>>>(x, Wq, Wk, Wv, Wqs, Wks, Wvs, xb, Wt);
  proj_kernel<<<dim3(3, 18, NH), 256, 0, stream>>>(xb, Wt, scal, qkv, vt);
  attn_kernel<<<dim3(2304), 256, 0, stream>>>(qkv, vt, out);
}